// Round 11
// baseline (260.269 us; speedup 1.0000x reference)
//
#include <hip/hip_runtime.h>

// GCN link predictor. fp32 math, bf16 intermediates + bf16 MFMA GEMM.
// Pipeline: CSR build (block-hist -> s1 -> stage[+inline bucket-base scan] -> scatter) ->
//           gemm1 -> FUSED[agg1+relu -> gemm2] -> agg2 -> decode.   (8 dispatches)
// norm factorization: h'[i] = dinv[i]*(x@W)[i];  z[i] = dinv[i]*(h'[i] + sum_{src->i} h'[src]) + b.
// R5: MFMA GEMM. R6 FAILED: hot global atomics. R7: deterministic-offset bucket CSR.
// R8: 248us. R9 FAILED: grid.sync ~60us each on 8 non-coherent XCDs. R10: quarter-wave gathers
// (neutral -> gathers at random-access floor ~5.9 TB/s logical).
// R11: ~80-90us of the 251us is dispatch gaps (~10us each x 10). Fuse agg1+gemm2 (z1 lives only
// in LDS: -1 dispatch, -25.6 MB traffic); fold bucket-base scan into stage (-1 dispatch).

typedef __attribute__((ext_vector_type(8))) short short8;   // 8 bf16 (A/B frag)
typedef __attribute__((ext_vector_type(4))) float floatx4;  // C/D frag

#define STAGE_G 128   // staging blocks

__device__ __forceinline__ unsigned short f2bf(float f) {
    union { float f; unsigned int u; } v; v.f = f;
    unsigned int u = v.u;
    u += 0x7fffu + ((u >> 16) & 1u);   // round-to-nearest-even
    return (unsigned short)(u >> 16);
}

__device__ __forceinline__ unsigned int pack2(float a, float b) {
    return (unsigned int)f2bf(a) | ((unsigned int)f2bf(b) << 16);
}

__device__ __forceinline__ float4 cvt4(unsigned int lo, unsigned int hi) {
    float4 f;
    f.x = __uint_as_float(lo << 16);
    f.y = __uint_as_float(lo & 0xffff0000u);
    f.z = __uint_as_float(hi << 16);
    f.w = __uint_as_float(hi & 0xffff0000u);
    return f;
}

// --- CSR build ---

__global__ __launch_bounds__(256) void block_hist_kernel(const int* __restrict__ dst,
                                                         int* __restrict__ bhist,
                                                         int E, int NB) {
    __shared__ int bh[1024];
    int t = threadIdx.x, g = blockIdx.x;
    for (int b = t; b < NB; b += 256) bh[b] = 0;
    __syncthreads();
    int chunk = (E + gridDim.x - 1) / gridDim.x;
    int lo = g * chunk, hi = min(lo + chunk, E);
    for (int i = lo + t; i < hi; i += 256) atomicAdd(&bh[dst[i] >> 6], 1);
    __syncthreads();
    for (int b = t; b < NB; b += 256) bhist[g * NB + b] = bh[b];
}

__global__ __launch_bounds__(128) void s1_scan_blocks(int* __restrict__ bhist,
                                                      int* __restrict__ T, int NB) {
    __shared__ int s[2][128];
    int b = blockIdx.x, t = threadIdx.x;
    int v = bhist[t * NB + b];
    int cur = 0;
    s[0][t] = v;
    __syncthreads();
#pragma unroll
    for (int off = 1; off < 128; off <<= 1) {
        int nxt = cur ^ 1;
        int val = s[cur][t];
        if (t >= off) val += s[cur][t - off];
        s[nxt][t] = val;
        __syncthreads();
        cur = nxt;
    }
    int inc = s[cur][t];
    bhist[t * NB + b] = inc - v;       // exclusive over blocks
    if (t == 127) T[b] = inc;
}

// Stage with inline bucket-base scan (was separate s2 kernel): each block redundantly
// exclusive-scans T[NB] (4 buckets/thread), block 0 also emits global bucket_base.
__global__ __launch_bounds__(256) void stage_kernel(const int* __restrict__ src,
                                                    const int* __restrict__ dst,
                                                    const int* __restrict__ bhist,
                                                    const int* __restrict__ T,
                                                    int* __restrict__ bucket_base,
                                                    unsigned int* __restrict__ stage,
                                                    int E, int NB) {
    __shared__ int lcur[1024];
    __shared__ int sb[2][256];
    int t = threadIdx.x, g = blockIdx.x;

    int b0 = t * 4;
    int v[4];
    int s = 0;
#pragma unroll
    for (int i = 0; i < 4; ++i) {
        int b = b0 + i;
        v[i] = (b < NB) ? T[b] : 0;
        s += v[i];
    }
    int cur = 0;
    sb[0][t] = s;
    __syncthreads();
#pragma unroll
    for (int off = 1; off < 256; off <<= 1) {
        int val = sb[cur][t];
        if (t >= off) val += sb[cur][t - off];
        sb[cur ^ 1][t] = val;
        __syncthreads();
        cur ^= 1;
    }
    int run = sb[cur][t] - s;   // exclusive base for bucket b0
#pragma unroll
    for (int i = 0; i < 4; ++i) {
        int b = b0 + i;
        if (b < NB) {
            lcur[b] = run + bhist[(size_t)g * NB + b];
            if (g == 0) bucket_base[b] = run;
        }
        run += v[i];
    }
    if (g == 0 && t == 255) bucket_base[NB] = run;   // == E
    __syncthreads();

    int chunk = (E + gridDim.x - 1) / gridDim.x;
    int lo = g * chunk, hi = min(lo + chunk, E);
    for (int i = lo + t; i < hi; i += 256) {
        int d = dst[i];
        int pos = atomicAdd(&lcur[d >> 6], 1);
        stage[pos] = ((unsigned int)src[i] << 6) | (unsigned int)(d & 63);
    }
}

__global__ __launch_bounds__(256) void scatter_kernel(const unsigned int* __restrict__ stage,
                                                      const int* __restrict__ bucket_base,
                                                      int* __restrict__ row_ptr,
                                                      float* __restrict__ dinv,
                                                      int* __restrict__ srcs_sorted,
                                                      int N) {
    __shared__ int cnt[64];
    __shared__ int lcur[64];
    int b = blockIdx.x, t = threadIdx.x;
    int lo = b << 6;
    int base = bucket_base[b], basen = bucket_base[b + 1];
    if (t < 64) cnt[t] = 0;
    __syncthreads();
    for (int i = base + t; i < basen; i += 256) atomicAdd(&cnt[stage[i] & 63u], 1);
    __syncthreads();
    if (t < 64) {
        int v = cnt[t];
        int inc = v;
#pragma unroll
        for (int off = 1; off < 64; off <<= 1) {
            int x = __shfl_up(inc, off, 64);
            if (t >= off) inc += x;
        }
        int exc = inc - v;
        int node = lo + t;
        if (node < N) {
            row_ptr[node] = base + exc;
            dinv[node] = rsqrtf((float)(v + 1));   // +1 self-loop
            if (node == N - 1) row_ptr[N] = base + exc + v;
        }
        lcur[t] = base + exc;
    }
    __syncthreads();
    for (int i = base + t; i < basen; i += 256) {
        unsigned int rec = stage[i];
        int pos = atomicAdd(&lcur[rec & 63u], 1);
        srcs_sorted[pos] = (int)(rec >> 6);
    }
}

// --- MFMA GEMM (layer 1): H[r][c] = bf16( dinv[r] * sum_k X[r][k]*W[k][c] ), 64x128/block ---
__global__ __launch_bounds__(256) void gemm_mfma_kernel(const float* __restrict__ Xv,
                                                        const float* __restrict__ W,
                                                        const float* __restrict__ dinv,
                                                        uint2* __restrict__ H, int N) {
    __shared__ __align__(16) char smem[50176];
    short* WB = (short*)smem;            // [nt][kt][lane][j]
    short* XL = (short*)(smem + 32768);  // [row][k], row stride 136 shorts
    float* Cst = (float*)smem;           // epilogue overlap: [row][col], stride 132 floats

    const int tid = threadIdx.x;
    const int w = tid >> 6;
    const int lane = tid & 63;
    const int blk = blockIdx.x;

    {
        const float4* W4 = (const float4*)W;
#pragma unroll
        for (int i = 0; i < 16; ++i) {
            int f = tid + i * 256;
            int k = f >> 5;
            int c4 = f & 31;
            float4 wv = W4[f];
            int kt = k >> 5, q = (k >> 3) & 3, j = k & 7;
            float e[4] = {wv.x, wv.y, wv.z, wv.w};
#pragma unroll
            for (int m = 0; m < 4; ++m) {
                int c = c4 * 4 + m;
                int nt = c >> 4;
                int ln = q * 16 + (c & 15);
                WB[((nt * 4 + kt) * 64 + ln) * 8 + j] = (short)f2bf(e[m]);
            }
        }
    }
    {
#pragma unroll
        for (int i = 0; i < 8; ++i) {
            int f = tid + i * 256;
            int row = f >> 5;
            int c4 = f & 31;
            int gr = min(blk * 64 + row, N - 1);
            float4 xv = ((const float4*)Xv)[(size_t)gr * 32 + c4];
            uint2 u;
            u.x = pack2(xv.x, xv.y);
            u.y = pack2(xv.z, xv.w);
            *(uint2*)&XL[row * 136 + c4 * 4] = u;
        }
    }
    __syncthreads();

    const int arow = w * 16 + (lane & 15);
    const int koff = (lane >> 4) * 8;
    short8 a[4];
#pragma unroll
    for (int kt = 0; kt < 4; ++kt)
        a[kt] = *(const short8*)&XL[arow * 136 + kt * 32 + koff];

    floatx4 acc[8];
#pragma unroll
    for (int nt = 0; nt < 8; ++nt) acc[nt] = (floatx4){0.f, 0.f, 0.f, 0.f};

#pragma unroll
    for (int kt = 0; kt < 4; ++kt) {
#pragma unroll
        for (int nt = 0; nt < 8; ++nt) {
            short8 b = *(const short8*)&WB[((nt * 4 + kt) * 64 + lane) * 8];
            acc[nt] = __builtin_amdgcn_mfma_f32_16x16x32_bf16(a[kt], b, acc[nt], 0, 0, 0);
        }
    }
    __syncthreads();

    {
        int q = lane >> 4, cn = lane & 15;
#pragma unroll
        for (int nt = 0; nt < 8; ++nt)
#pragma unroll
            for (int r = 0; r < 4; ++r)
                Cst[(w * 16 + q * 4 + r) * 132 + nt * 16 + cn] = acc[nt][r];
    }
    __syncthreads();
    {
#pragma unroll
        for (int i = 0; i < 8; ++i) {
            int f = tid + i * 256;
            int row = f >> 5;
            int c4 = f & 31;
            int gr = blk * 64 + row;
            if (gr < N) {
                float4 v = *(float4*)&Cst[row * 132 + c4 * 4];
                float di = dinv[gr];
                uint2 o;
                o.x = pack2(v.x * di, v.y * di);
                o.y = pack2(v.z * di, v.w * di);
                H[(size_t)gr * 32 + c4] = o;
            }
        }
    }
}

// --- FUSED agg1(+relu) -> gemm2: per 64-row tile, aggregate z1 into the XL LDS operand
// (z1 never touches global), then MFMA z1@W2 with dinv epilogue -> h2' bf16 global.
__global__ __launch_bounds__(256) void agg_gemm_kernel(const unsigned short* __restrict__ Hp,
                                                       const int* __restrict__ row_ptr,
                                                       const int* __restrict__ srcs,
                                                       const float* __restrict__ dinv,
                                                       const float* __restrict__ bias1,
                                                       const float* __restrict__ W2,
                                                       uint2* __restrict__ Hout, int N) {
    __shared__ __align__(16) char smem[50176];
    short* WB = (short*)smem;            // W2 B-frag layout (bf16)
    short* XL = (short*)(smem + 32768);  // z1 tile [row][k], stride 136 shorts
    float* Cst = (float*)smem;           // epilogue overlay

    const int tid = threadIdx.x;
    const int blk = blockIdx.x;

    // stage W2 -> WB (same layout as gemm)
    {
        const float4* W4 = (const float4*)W2;
#pragma unroll
        for (int i = 0; i < 16; ++i) {
            int f = tid + i * 256;
            int k = f >> 5;
            int c4 = f & 31;
            float4 wv = W4[f];
            int kt = k >> 5, q = (k >> 3) & 3, j = k & 7;
            float e[4] = {wv.x, wv.y, wv.z, wv.w};
#pragma unroll
            for (int m = 0; m < 4; ++m) {
                int c = c4 * 4 + m;
                int nt = c >> 4;
                int ln = q * 16 + (c & 15);
                WB[((nt * 4 + kt) * 64 + ln) * 8 + j] = (short)f2bf(e[m]);
            }
        }
    }

    // agg phase: 16 quarter-waves, 4 nodes each (rows qw, qw+16, qw+32, qw+48)
    {
        int qw = tid >> 4;
        int hl = tid & 15;
        const uint4* H4 = (const uint4*)Hp;
        float4 bv0 = ((const float4*)bias1)[2 * hl];
        float4 bv1 = ((const float4*)bias1)[2 * hl + 1];
#pragma unroll
        for (int r = 0; r < 4; ++r) {
            int idx = qw + 16 * r;
            int n = blk * 64 + idx;
            uint4 o;
            if (n < N) {
                uint4 us = H4[(size_t)n * 16 + hl];   // self-loop
                float4 a0 = cvt4(us.x, us.y);
                float4 a1 = cvt4(us.z, us.w);
                float4 c0 = make_float4(0.f, 0.f, 0.f, 0.f);
                float4 c1 = make_float4(0.f, 0.f, 0.f, 0.f);
                int j = row_ptr[n], end = row_ptr[n + 1];
                for (; j + 3 < end; j += 4) {
                    uint4 u0 = H4[(size_t)srcs[j + 0] * 16 + hl];
                    uint4 u1 = H4[(size_t)srcs[j + 1] * 16 + hl];
                    uint4 u2 = H4[(size_t)srcs[j + 2] * 16 + hl];
                    uint4 u3 = H4[(size_t)srcs[j + 3] * 16 + hl];
                    float4 t;
                    t = cvt4(u0.x, u0.y); a0.x += t.x; a0.y += t.y; a0.z += t.z; a0.w += t.w;
                    t = cvt4(u0.z, u0.w); a1.x += t.x; a1.y += t.y; a1.z += t.z; a1.w += t.w;
                    t = cvt4(u1.x, u1.y); c0.x += t.x; c0.y += t.y; c0.z += t.z; c0.w += t.w;
                    t = cvt4(u1.z, u1.w); c1.x += t.x; c1.y += t.y; c1.z += t.z; c1.w += t.w;
                    t = cvt4(u2.x, u2.y); a0.x += t.x; a0.y += t.y; a0.z += t.z; a0.w += t.w;
                    t = cvt4(u2.z, u2.w); a1.x += t.x; a1.y += t.y; a1.z += t.z; a1.w += t.w;
                    t = cvt4(u3.x, u3.y); c0.x += t.x; c0.y += t.y; c0.z += t.z; c0.w += t.w;
                    t = cvt4(u3.z, u3.w); c1.x += t.x; c1.y += t.y; c1.z += t.z; c1.w += t.w;
                }
                for (; j < end; ++j) {
                    uint4 u = H4[(size_t)srcs[j] * 16 + hl];
                    float4 t;
                    t = cvt4(u.x, u.y); a0.x += t.x; a0.y += t.y; a0.z += t.z; a0.w += t.w;
                    t = cvt4(u.z, u.w); a1.x += t.x; a1.y += t.y; a1.z += t.z; a1.w += t.w;
                }
                a0.x += c0.x; a0.y += c0.y; a0.z += c0.z; a0.w += c0.w;
                a1.x += c1.x; a1.y += c1.y; a1.z += c1.z; a1.w += c1.w;
                float di = dinv[n];
                float o0 = fmaxf(di * a0.x + bv0.x, 0.f);
                float o1 = fmaxf(di * a0.y + bv0.y, 0.f);
                float o2 = fmaxf(di * a0.z + bv0.z, 0.f);
                float o3 = fmaxf(di * a0.w + bv0.w, 0.f);
                float o4 = fmaxf(di * a1.x + bv1.x, 0.f);
                float o5 = fmaxf(di * a1.y + bv1.y, 0.f);
                float o6 = fmaxf(di * a1.z + bv1.z, 0.f);
                float o7 = fmaxf(di * a1.w + bv1.w, 0.f);
                o.x = pack2(o0, o1);
                o.y = pack2(o2, o3);
                o.z = pack2(o4, o5);
                o.w = pack2(o6, o7);
            } else {
                o = make_uint4(0u, 0u, 0u, 0u);
            }
            *(uint4*)&XL[idx * 136 + hl * 8] = o;   // z1 row, bf16, k-contiguous
        }
    }
    __syncthreads();

    // MFMA phase (identical to gemm): z1 @ W2
    const int w = tid >> 6;
    const int lane = tid & 63;
    const int arow = w * 16 + (lane & 15);
    const int koff = (lane >> 4) * 8;
    short8 a[4];
#pragma unroll
    for (int kt = 0; kt < 4; ++kt)
        a[kt] = *(const short8*)&XL[arow * 136 + kt * 32 + koff];

    floatx4 acc[8];
#pragma unroll
    for (int nt = 0; nt < 8; ++nt) acc[nt] = (floatx4){0.f, 0.f, 0.f, 0.f};

#pragma unroll
    for (int kt = 0; kt < 4; ++kt) {
#pragma unroll
        for (int nt = 0; nt < 8; ++nt) {
            short8 b = *(const short8*)&WB[((nt * 4 + kt) * 64 + lane) * 8];
            acc[nt] = __builtin_amdgcn_mfma_f32_16x16x32_bf16(a[kt], b, acc[nt], 0, 0, 0);
        }
    }
    __syncthreads();

    {
        int q = lane >> 4, cn = lane & 15;
#pragma unroll
        for (int nt = 0; nt < 8; ++nt)
#pragma unroll
            for (int r = 0; r < 4; ++r)
                Cst[(w * 16 + q * 4 + r) * 132 + nt * 16 + cn] = acc[nt][r];
    }
    __syncthreads();
    {
#pragma unroll
        for (int i = 0; i < 8; ++i) {
            int f = tid + i * 256;
            int row = f >> 5;
            int c4 = f & 31;
            int gr = blk * 64 + row;
            if (gr < N) {
                float4 v = *(float4*)&Cst[row * 132 + c4 * 4];
                float di = dinv[gr];
                uint2 o;
                o.x = pack2(v.x * di, v.y * di);
                o.y = pack2(v.z * di, v.w * di);
                Hout[(size_t)gr * 32 + c4] = o;
            }
        }
    }
}

// Quarter-wave (16 lanes) per node; lane holds 8 cols as uint4. fp32 accumulate.
__global__ __launch_bounds__(256) void agg_kernel(const unsigned short* __restrict__ Hp,
                                                  const int* __restrict__ row_ptr,
                                                  const int* __restrict__ srcs,
                                                  const float* __restrict__ dinv,
                                                  const float* __restrict__ bias,
                                                  unsigned short* __restrict__ Z,
                                                  int N, int do_relu) {
    int gw = (int)((blockIdx.x * blockDim.x + threadIdx.x) >> 6);
    int lane = threadIdx.x & 63;
    int q = lane >> 4;
    int hl = lane & 15;
    int n = gw * 4 + q;
    if (n >= N) return;

    const uint4* H4 = (const uint4*)Hp;
    uint4 us = H4[(size_t)n * 16 + hl];
    float4 a0 = cvt4(us.x, us.y);
    float4 a1 = cvt4(us.z, us.w);
    float4 b0 = make_float4(0.f, 0.f, 0.f, 0.f);
    float4 b1 = make_float4(0.f, 0.f, 0.f, 0.f);

    int j = row_ptr[n], end = row_ptr[n + 1];
    for (; j + 7 < end; j += 8) {
        uint4 u0 = H4[(size_t)srcs[j + 0] * 16 + hl];
        uint4 u1 = H4[(size_t)srcs[j + 1] * 16 + hl];
        uint4 u2 = H4[(size_t)srcs[j + 2] * 16 + hl];
        uint4 u3 = H4[(size_t)srcs[j + 3] * 16 + hl];
        uint4 u4 = H4[(size_t)srcs[j + 4] * 16 + hl];
        uint4 u5 = H4[(size_t)srcs[j + 5] * 16 + hl];
        uint4 u6 = H4[(size_t)srcs[j + 6] * 16 + hl];
        uint4 u7 = H4[(size_t)srcs[j + 7] * 16 + hl];
        float4 t;
        t = cvt4(u0.x, u0.y); a0.x += t.x; a0.y += t.y; a0.z += t.z; a0.w += t.w;
        t = cvt4(u0.z, u0.w); a1.x += t.x; a1.y += t.y; a1.z += t.z; a1.w += t.w;
        t = cvt4(u1.x, u1.y); b0.x += t.x; b0.y += t.y; b0.z += t.z; b0.w += t.w;
        t = cvt4(u1.z, u1.w); b1.x += t.x; b1.y += t.y; b1.z += t.z; b1.w += t.w;
        t = cvt4(u2.x, u2.y); a0.x += t.x; a0.y += t.y; a0.z += t.z; a0.w += t.w;
        t = cvt4(u2.z, u2.w); a1.x += t.x; a1.y += t.y; a1.z += t.z; a1.w += t.w;
        t = cvt4(u3.x, u3.y); b0.x += t.x; b0.y += t.y; b0.z += t.z; b0.w += t.w;
        t = cvt4(u3.z, u3.w); b1.x += t.x; b1.y += t.y; b1.z += t.z; b1.w += t.w;
        t = cvt4(u4.x, u4.y); a0.x += t.x; a0.y += t.y; a0.z += t.z; a0.w += t.w;
        t = cvt4(u4.z, u4.w); a1.x += t.x; a1.y += t.y; a1.z += t.z; a1.w += t.w;
        t = cvt4(u5.x, u5.y); b0.x += t.x; b0.y += t.y; b0.z += t.z; b0.w += t.w;
        t = cvt4(u5.z, u5.w); b1.x += t.x; b1.y += t.y; b1.z += t.z; b1.w += t.w;
        t = cvt4(u6.x, u6.y); a0.x += t.x; a0.y += t.y; a0.z += t.z; a0.w += t.w;
        t = cvt4(u6.z, u6.w); a1.x += t.x; a1.y += t.y; a1.z += t.z; a1.w += t.w;
        t = cvt4(u7.x, u7.y); b0.x += t.x; b0.y += t.y; b0.z += t.z; b0.w += t.w;
        t = cvt4(u7.z, u7.w); b1.x += t.x; b1.y += t.y; b1.z += t.z; b1.w += t.w;
    }
    for (; j + 3 < end; j += 4) {
        uint4 u0 = H4[(size_t)srcs[j + 0] * 16 + hl];
        uint4 u1 = H4[(size_t)srcs[j + 1] * 16 + hl];
        uint4 u2 = H4[(size_t)srcs[j + 2] * 16 + hl];
        uint4 u3 = H4[(size_t)srcs[j + 3] * 16 + hl];
        float4 t;
        t = cvt4(u0.x, u0.y); a0.x += t.x; a0.y += t.y; a0.z += t.z; a0.w += t.w;
        t = cvt4(u0.z, u0.w); a1.x += t.x; a1.y += t.y; a1.z += t.z; a1.w += t.w;
        t = cvt4(u1.x, u1.y); b0.x += t.x; b0.y += t.y; b0.z += t.z; b0.w += t.w;
        t = cvt4(u1.z, u1.w); b1.x += t.x; b1.y += t.y; b1.z += t.z; b1.w += t.w;
        t = cvt4(u2.x, u2.y); a0.x += t.x; a0.y += t.y; a0.z += t.z; a0.w += t.w;
        t = cvt4(u2.z, u2.w); a1.x += t.x; a1.y += t.y; a1.z += t.z; a1.w += t.w;
        t = cvt4(u3.x, u3.y); b0.x += t.x; b0.y += t.y; b0.z += t.z; b0.w += t.w;
        t = cvt4(u3.z, u3.w); b1.x += t.x; b1.y += t.y; b1.z += t.z; b1.w += t.w;
    }
    for (; j < end; ++j) {
        uint4 u = H4[(size_t)srcs[j] * 16 + hl];
        float4 t;
        t = cvt4(u.x, u.y); a0.x += t.x; a0.y += t.y; a0.z += t.z; a0.w += t.w;
        t = cvt4(u.z, u.w); a1.x += t.x; a1.y += t.y; a1.z += t.z; a1.w += t.w;
    }
    a0.x += b0.x; a0.y += b0.y; a0.z += b0.z; a0.w += b0.w;
    a1.x += b1.x; a1.y += b1.y; a1.z += b1.z; a1.w += b1.w;

    float di = dinv[n];
    float4 bv0 = ((const float4*)bias)[2 * hl];
    float4 bv1 = ((const float4*)bias)[2 * hl + 1];
    float o0 = di * a0.x + bv0.x, o1 = di * a0.y + bv0.y;
    float o2 = di * a0.z + bv0.z, o3 = di * a0.w + bv0.w;
    float o4 = di * a1.x + bv1.x, o5 = di * a1.y + bv1.y;
    float o6 = di * a1.z + bv1.z, o7 = di * a1.w + bv1.w;
    if (do_relu) {
        o0 = fmaxf(o0, 0.f); o1 = fmaxf(o1, 0.f); o2 = fmaxf(o2, 0.f); o3 = fmaxf(o3, 0.f);
        o4 = fmaxf(o4, 0.f); o5 = fmaxf(o5, 0.f); o6 = fmaxf(o6, 0.f); o7 = fmaxf(o7, 0.f);
    }
    uint4 o;
    o.x = pack2(o0, o1);
    o.y = pack2(o2, o3);
    o.z = pack2(o4, o5);
    o.w = pack2(o6, o7);
    ((uint4*)Z)[(size_t)n * 16 + hl] = o;
}

// Decode: quarter-wave, 2 pairs per quarter -> 8 pairs/wave.
__global__ __launch_bounds__(256) void decode_kernel(const unsigned short* __restrict__ Z,
                                                     const int* __restrict__ pa,
                                                     const int* __restrict__ pb,
                                                     float* __restrict__ out, int P) {
    int wv = (int)((blockIdx.x * blockDim.x + threadIdx.x) >> 6);
    int lane = threadIdx.x & 63;
    int q = lane >> 4;
    int hl = lane & 15;
    int p0 = wv * 8 + q * 2;
    if (p0 >= P) return;
    const uint4* Z4 = (const uint4*)Z;

    bool two = (p0 + 1 < P);
    int A0 = pa[p0], B0 = pb[p0];
    int A1 = two ? pa[p0 + 1] : A0;
    int B1 = two ? pb[p0 + 1] : B0;
    uint4 ua0 = Z4[(size_t)A0 * 16 + hl];
    uint4 ub0 = Z4[(size_t)B0 * 16 + hl];
    uint4 ua1 = Z4[(size_t)A1 * 16 + hl];
    uint4 ub1 = Z4[(size_t)B1 * 16 + hl];

    float4 xa, xb, ya, yb;
    xa = cvt4(ua0.x, ua0.y); xb = cvt4(ub0.x, ub0.y);
    ya = cvt4(ua0.z, ua0.w); yb = cvt4(ub0.z, ub0.w);
    float v0 = xa.x * xb.x + xa.y * xb.y + xa.z * xb.z + xa.w * xb.w
             + ya.x * yb.x + ya.y * yb.y + ya.z * yb.z + ya.w * yb.w;
    xa = cvt4(ua1.x, ua1.y); xb = cvt4(ub1.x, ub1.y);
    ya = cvt4(ua1.z, ua1.w); yb = cvt4(ub1.z, ub1.w);
    float v1 = xa.x * xb.x + xa.y * xb.y + xa.z * xb.z + xa.w * xb.w
             + ya.x * yb.x + ya.y * yb.y + ya.z * yb.z + ya.w * yb.w;
#pragma unroll
    for (int off = 8; off > 0; off >>= 1) {
        v0 += __shfl_down(v0, off, 16);
        v1 += __shfl_down(v1, off, 16);
    }
    if (hl == 0) {
        out[p0] = v0;
        if (two) out[p0 + 1] = v1;
    }
}

extern "C" void kernel_launch(void* const* d_in, const int* in_sizes, int n_in,
                              void* d_out, int out_size, void* d_ws, size_t ws_size,
                              hipStream_t stream) {
    const int*   edge_index = (const int*)d_in[0];
    const int*   edge_pairs = (const int*)d_in[1];
    const float* emb        = (const float*)d_in[2];
    const float* W1         = (const float*)d_in[3];
    const float* b1         = (const float*)d_in[4];
    const float* W2         = (const float*)d_in[5];
    const float* b2         = (const float*)d_in[6];
    float* out = (float*)d_out;

    int E = in_sizes[0] / 2;
    int P = in_sizes[1] / 2;
    int N = in_sizes[2] / 128;
    int NB = (N + 63) / 64;    // buckets (782 for N=50000; must be <= 1024)

    const int* src = edge_index;
    const int* dst = edge_index + E;
    const int* pa  = edge_pairs;
    const int* pb  = edge_pairs + P;

    char* ws = (char*)d_ws;
    size_t off = 0;
    auto alloc = [&](size_t bytes) -> void* {
        void* p = ws + off;
        off = (off + bytes + 255) & ~(size_t)255;
        return p;
    };
    unsigned short* bufA = (unsigned short*)alloc((size_t)N * 128 * 2); // h1' then z2 (bf16)
    unsigned short* bufB = (unsigned short*)alloc((size_t)N * 128 * 2); // h2' (bf16)
    int*   srcs_sorted  = (int*)alloc((size_t)E * sizeof(int));
    unsigned int* stage = (unsigned int*)alloc((size_t)E * sizeof(unsigned int));
    int*   row_ptr      = (int*)alloc((size_t)(N + 1) * sizeof(int));
    float* dinv         = (float*)alloc((size_t)N * sizeof(float));
    int*   bhist        = (int*)alloc((size_t)STAGE_G * NB * sizeof(int));
    int*   T            = (int*)alloc((size_t)NB * sizeof(int));
    int*   bucket_base  = (int*)alloc((size_t)(NB + 1) * sizeof(int));

    // CSR build (4 dispatches)
    block_hist_kernel<<<STAGE_G, 256, 0, stream>>>(dst, bhist, E, NB);
    s1_scan_blocks<<<NB, 128, 0, stream>>>(bhist, T, NB);
    stage_kernel<<<STAGE_G, 256, 0, stream>>>(src, dst, bhist, T, bucket_base, stage, E, NB);
    scatter_kernel<<<NB, 256, 0, stream>>>(stage, bucket_base, row_ptr, dinv, srcs_sorted, N);

    // Layer 1 GEMM: h1' = dinv*(emb@W1) -> bufA
    gemm_mfma_kernel<<<(N + 63) / 64, 256, 0, stream>>>(emb, W1, dinv, (uint2*)bufA, N);

    // FUSED: agg1(+b1,relu) in LDS -> gemm2 -> h2' = dinv*(z1@W2) -> bufB
    agg_gemm_kernel<<<(N + 63) / 64, 256, 0, stream>>>(bufA, row_ptr, srcs_sorted, dinv,
                                                       b1, W2, (uint2*)bufB, N);

    // Layer 2 agg: z2 = dinv*(h2'+sum)+b2 -> bufA
    agg_kernel<<<(N + 15) / 16, 256, 0, stream>>>(bufB, row_ptr, srcs_sorted, dinv, b2,
                                                  (unsigned short*)bufA, N, 0);

    // Decode: 8 pairs/wave
    decode_kernel<<<(P + 31) / 32, 256, 0, stream>>>((unsigned short*)bufA, pa, pb, out, P);
}

// Round 12
// 248.012 us; speedup vs baseline: 1.0494x; 1.0494x over previous
//
#include <hip/hip_runtime.h>

// GCN link predictor. fp32 math, bf16 intermediates + bf16 MFMA GEMM.
// Pipeline: block-hist -> s1 -> stage[+inline bucket-base scan] -> FUSED[scatter+gemm1] ->
//           agg1 -> gemm2 -> agg2 -> decode.   (8 dispatches)
// norm factorization: h'[i] = dinv[i]*(x@W)[i];  z[i] = dinv[i]*(h'[i] + sum_{src->i} h'[src]) + b.
// R5: MFMA GEMM. R6 FAILED: hot global atomics. R7: deterministic-offset bucket CSR. R8: 248us.
// R9 FAILED: grid.sync ~60us/ea. R10: quarter-wave gathers (neutral; gathers at random-access
// floor). R11 FAILED: agg1+gemm2 fusion cut gather parallelism 4x (71us vs 45us unfused).
// R12: fuse scatter+gemm1 instead -- SAME 782-block grid over the SAME 64-node ranges, so no
// parallelism loss; dinv flows scatter->gemm through LDS.

typedef __attribute__((ext_vector_type(8))) short short8;   // 8 bf16 (A/B frag)
typedef __attribute__((ext_vector_type(4))) float floatx4;  // C/D frag

#define STAGE_G 128   // staging blocks

__device__ __forceinline__ unsigned short f2bf(float f) {
    union { float f; unsigned int u; } v; v.f = f;
    unsigned int u = v.u;
    u += 0x7fffu + ((u >> 16) & 1u);   // round-to-nearest-even
    return (unsigned short)(u >> 16);
}

__device__ __forceinline__ unsigned int pack2(float a, float b) {
    return (unsigned int)f2bf(a) | ((unsigned int)f2bf(b) << 16);
}

__device__ __forceinline__ float4 cvt4(unsigned int lo, unsigned int hi) {
    float4 f;
    f.x = __uint_as_float(lo << 16);
    f.y = __uint_as_float(lo & 0xffff0000u);
    f.z = __uint_as_float(hi << 16);
    f.w = __uint_as_float(hi & 0xffff0000u);
    return f;
}

// --- CSR build ---

__global__ __launch_bounds__(256) void block_hist_kernel(const int* __restrict__ dst,
                                                         int* __restrict__ bhist,
                                                         int E, int NB) {
    __shared__ int bh[1024];
    int t = threadIdx.x, g = blockIdx.x;
    for (int b = t; b < NB; b += 256) bh[b] = 0;
    __syncthreads();
    int chunk = (E + gridDim.x - 1) / gridDim.x;
    int lo = g * chunk, hi = min(lo + chunk, E);
    for (int i = lo + t; i < hi; i += 256) atomicAdd(&bh[dst[i] >> 6], 1);
    __syncthreads();
    for (int b = t; b < NB; b += 256) bhist[g * NB + b] = bh[b];
}

__global__ __launch_bounds__(128) void s1_scan_blocks(int* __restrict__ bhist,
                                                      int* __restrict__ T, int NB) {
    __shared__ int s[2][128];
    int b = blockIdx.x, t = threadIdx.x;
    int v = bhist[t * NB + b];
    int cur = 0;
    s[0][t] = v;
    __syncthreads();
#pragma unroll
    for (int off = 1; off < 128; off <<= 1) {
        int nxt = cur ^ 1;
        int val = s[cur][t];
        if (t >= off) val += s[cur][t - off];
        s[nxt][t] = val;
        __syncthreads();
        cur = nxt;
    }
    int inc = s[cur][t];
    bhist[t * NB + b] = inc - v;       // exclusive over blocks
    if (t == 127) T[b] = inc;
}

// Stage with inline bucket-base scan: each block redundantly exclusive-scans T[NB]
// (4 buckets/thread); block 0 also emits global bucket_base.
__global__ __launch_bounds__(256) void stage_kernel(const int* __restrict__ src,
                                                    const int* __restrict__ dst,
                                                    const int* __restrict__ bhist,
                                                    const int* __restrict__ T,
                                                    int* __restrict__ bucket_base,
                                                    unsigned int* __restrict__ stage,
                                                    int E, int NB) {
    __shared__ int lcur[1024];
    __shared__ int sb[2][256];
    int t = threadIdx.x, g = blockIdx.x;

    int b0 = t * 4;
    int v[4];
    int s = 0;
#pragma unroll
    for (int i = 0; i < 4; ++i) {
        int b = b0 + i;
        v[i] = (b < NB) ? T[b] : 0;
        s += v[i];
    }
    int cur = 0;
    sb[0][t] = s;
    __syncthreads();
#pragma unroll
    for (int off = 1; off < 256; off <<= 1) {
        int val = sb[cur][t];
        if (t >= off) val += sb[cur][t - off];
        sb[cur ^ 1][t] = val;
        __syncthreads();
        cur ^= 1;
    }
    int run = sb[cur][t] - s;   // exclusive base for bucket b0
#pragma unroll
    for (int i = 0; i < 4; ++i) {
        int b = b0 + i;
        if (b < NB) {
            lcur[b] = run + bhist[(size_t)g * NB + b];
            if (g == 0) bucket_base[b] = run;
        }
        run += v[i];
    }
    if (g == 0 && t == 255) bucket_base[NB] = run;   // == E
    __syncthreads();

    int chunk = (E + gridDim.x - 1) / gridDim.x;
    int lo = g * chunk, hi = min(lo + chunk, E);
    for (int i = lo + t; i < hi; i += 256) {
        int d = dst[i];
        int pos = atomicAdd(&lcur[d >> 6], 1);
        stage[pos] = ((unsigned int)src[i] << 6) | (unsigned int)(d & 63);
    }
}

// --- FUSED scatter + layer-1 GEMM. One block per bucket b == one 64-row gemm tile.
// Phase 1: scatter bucket b -> srcs_sorted, row_ptr, dinv (global + LDS).
// Phase 2: H[r][c] = bf16( dinv[r] * sum_k X[r][k]*W1[k][c] ) for rows 64b..64b+63.
__global__ __launch_bounds__(256) void scatter_gemm_kernel(const unsigned int* __restrict__ stage,
                                                           const int* __restrict__ bucket_base,
                                                           int* __restrict__ row_ptr,
                                                           float* __restrict__ dinv,
                                                           int* __restrict__ srcs_sorted,
                                                           const float* __restrict__ Xv,
                                                           const float* __restrict__ W,
                                                           uint2* __restrict__ H, int N) {
    __shared__ __align__(16) char smem[50176];
    __shared__ int cnt[64];
    __shared__ int lcur[64];
    __shared__ float sdinv[64];
    short* WB = (short*)smem;            // [nt][kt][lane][j]
    short* XL = (short*)(smem + 32768);  // [row][k], row stride 136 shorts
    float* Cst = (float*)smem;           // epilogue overlay: [row][col], stride 132 floats

    const int tid = threadIdx.x;
    const int blk = blockIdx.x;

    // ---- Phase 1: scatter bucket blk ----
    {
        int t = tid;
        int lo = blk << 6;
        int base = bucket_base[blk], basen = bucket_base[blk + 1];
        if (t < 64) cnt[t] = 0;
        __syncthreads();
        for (int i = base + t; i < basen; i += 256) atomicAdd(&cnt[stage[i] & 63u], 1);
        __syncthreads();
        if (t < 64) {
            int v = cnt[t];
            int inc = v;
#pragma unroll
            for (int off = 1; off < 64; off <<= 1) {
                int x = __shfl_up(inc, off, 64);
                if (t >= off) inc += x;
            }
            int exc = inc - v;
            int node = lo + t;
            float di = rsqrtf((float)(v + 1));   // +1 self-loop
            if (node < N) {
                row_ptr[node] = base + exc;
                dinv[node] = di;
                if (node == N - 1) row_ptr[N] = base + exc + v;
                sdinv[t] = di;
            } else {
                sdinv[t] = 0.f;
            }
            lcur[t] = base + exc;
        }
        __syncthreads();
        for (int i = base + t; i < basen; i += 256) {
            unsigned int rec = stage[i];
            int pos = atomicAdd(&lcur[rec & 63u], 1);
            srcs_sorted[pos] = (int)(rec >> 6);
        }
    }
    __syncthreads();

    // ---- Phase 2: gemm1 (fp32 X @ W -> bf16 H, dinv from LDS) ----
    {
        const float4* W4 = (const float4*)W;
#pragma unroll
        for (int i = 0; i < 16; ++i) {
            int f = tid + i * 256;
            int k = f >> 5;
            int c4 = f & 31;
            float4 wv = W4[f];
            int kt = k >> 5, q = (k >> 3) & 3, j = k & 7;
            float e[4] = {wv.x, wv.y, wv.z, wv.w};
#pragma unroll
            for (int m = 0; m < 4; ++m) {
                int c = c4 * 4 + m;
                int nt = c >> 4;
                int ln = q * 16 + (c & 15);
                WB[((nt * 4 + kt) * 64 + ln) * 8 + j] = (short)f2bf(e[m]);
            }
        }
    }
    {
#pragma unroll
        for (int i = 0; i < 8; ++i) {
            int f = tid + i * 256;
            int row = f >> 5;
            int c4 = f & 31;
            int gr = min(blk * 64 + row, N - 1);
            float4 xv = ((const float4*)Xv)[(size_t)gr * 32 + c4];
            uint2 u;
            u.x = pack2(xv.x, xv.y);
            u.y = pack2(xv.z, xv.w);
            *(uint2*)&XL[row * 136 + c4 * 4] = u;
        }
    }
    __syncthreads();

    const int w = tid >> 6;
    const int lane = tid & 63;
    const int arow = w * 16 + (lane & 15);
    const int koff = (lane >> 4) * 8;
    short8 a[4];
#pragma unroll
    for (int kt = 0; kt < 4; ++kt)
        a[kt] = *(const short8*)&XL[arow * 136 + kt * 32 + koff];

    floatx4 acc[8];
#pragma unroll
    for (int nt = 0; nt < 8; ++nt) acc[nt] = (floatx4){0.f, 0.f, 0.f, 0.f};

#pragma unroll
    for (int kt = 0; kt < 4; ++kt) {
#pragma unroll
        for (int nt = 0; nt < 8; ++nt) {
            short8 b = *(const short8*)&WB[((nt * 4 + kt) * 64 + lane) * 8];
            acc[nt] = __builtin_amdgcn_mfma_f32_16x16x32_bf16(a[kt], b, acc[nt], 0, 0, 0);
        }
    }
    __syncthreads();

    {
        int q = lane >> 4, cn = lane & 15;
#pragma unroll
        for (int nt = 0; nt < 8; ++nt)
#pragma unroll
            for (int r = 0; r < 4; ++r)
                Cst[(w * 16 + q * 4 + r) * 132 + nt * 16 + cn] = acc[nt][r];
    }
    __syncthreads();
    {
#pragma unroll
        for (int i = 0; i < 8; ++i) {
            int f = tid + i * 256;
            int row = f >> 5;
            int c4 = f & 31;
            int gr = blk * 64 + row;
            if (gr < N) {
                float4 v = *(float4*)&Cst[row * 132 + c4 * 4];
                float di = sdinv[row];
                uint2 o;
                o.x = pack2(v.x * di, v.y * di);
                o.y = pack2(v.z * di, v.w * di);
                H[(size_t)gr * 32 + c4] = o;
            }
        }
    }
}

// --- standalone MFMA GEMM (layer 2, bf16 input) ---
__global__ __launch_bounds__(256) void gemm_mfma_kernel(const unsigned short* __restrict__ Xv,
                                                        const float* __restrict__ W,
                                                        const float* __restrict__ dinv,
                                                        uint2* __restrict__ H, int N) {
    __shared__ __align__(16) char smem[50176];
    short* WB = (short*)smem;
    short* XL = (short*)(smem + 32768);
    float* Cst = (float*)smem;

    const int tid = threadIdx.x;
    const int w = tid >> 6;
    const int lane = tid & 63;
    const int blk = blockIdx.x;

    {
        const float4* W4 = (const float4*)W;
#pragma unroll
        for (int i = 0; i < 16; ++i) {
            int f = tid + i * 256;
            int k = f >> 5;
            int c4 = f & 31;
            float4 wv = W4[f];
            int kt = k >> 5, q = (k >> 3) & 3, j = k & 7;
            float e[4] = {wv.x, wv.y, wv.z, wv.w};
#pragma unroll
            for (int m = 0; m < 4; ++m) {
                int c = c4 * 4 + m;
                int nt = c >> 4;
                int ln = q * 16 + (c & 15);
                WB[((nt * 4 + kt) * 64 + ln) * 8 + j] = (short)f2bf(e[m]);
            }
        }
    }
    {
#pragma unroll
        for (int i = 0; i < 8; ++i) {
            int f = tid + i * 256;
            int row = f >> 5;
            int c4 = f & 31;
            int gr = min(blk * 64 + row, N - 1);
            uint2 u = ((const uint2*)Xv)[(size_t)gr * 32 + c4];
            *(uint2*)&XL[row * 136 + c4 * 4] = u;
        }
    }
    __syncthreads();

    const int arow = w * 16 + (lane & 15);
    const int koff = (lane >> 4) * 8;
    short8 a[4];
#pragma unroll
    for (int kt = 0; kt < 4; ++kt)
        a[kt] = *(const short8*)&XL[arow * 136 + kt * 32 + koff];

    floatx4 acc[8];
#pragma unroll
    for (int nt = 0; nt < 8; ++nt) acc[nt] = (floatx4){0.f, 0.f, 0.f, 0.f};

#pragma unroll
    for (int kt = 0; kt < 4; ++kt) {
#pragma unroll
        for (int nt = 0; nt < 8; ++nt) {
            short8 b = *(const short8*)&WB[((nt * 4 + kt) * 64 + lane) * 8];
            acc[nt] = __builtin_amdgcn_mfma_f32_16x16x32_bf16(a[kt], b, acc[nt], 0, 0, 0);
        }
    }
    __syncthreads();

    {
        int q = lane >> 4, cn = lane & 15;
#pragma unroll
        for (int nt = 0; nt < 8; ++nt)
#pragma unroll
            for (int r = 0; r < 4; ++r)
                Cst[(w * 16 + q * 4 + r) * 132 + nt * 16 + cn] = acc[nt][r];
    }
    __syncthreads();
    {
#pragma unroll
        for (int i = 0; i < 8; ++i) {
            int f = tid + i * 256;
            int row = f >> 5;
            int c4 = f & 31;
            int gr = blk * 64 + row;
            if (gr < N) {
                float4 v = *(float4*)&Cst[row * 132 + c4 * 4];
                float di = dinv[gr];
                uint2 o;
                o.x = pack2(v.x * di, v.y * di);
                o.y = pack2(v.z * di, v.w * di);
                H[(size_t)gr * 32 + c4] = o;
            }
        }
    }
}

// Quarter-wave (16 lanes) per node; lane holds 8 cols as uint4. fp32 accumulate.
__global__ __launch_bounds__(256) void agg_kernel(const unsigned short* __restrict__ Hp,
                                                  const int* __restrict__ row_ptr,
                                                  const int* __restrict__ srcs,
                                                  const float* __restrict__ dinv,
                                                  const float* __restrict__ bias,
                                                  unsigned short* __restrict__ Z,
                                                  int N, int do_relu) {
    int gw = (int)((blockIdx.x * blockDim.x + threadIdx.x) >> 6);
    int lane = threadIdx.x & 63;
    int q = lane >> 4;
    int hl = lane & 15;
    int n = gw * 4 + q;
    if (n >= N) return;

    const uint4* H4 = (const uint4*)Hp;
    uint4 us = H4[(size_t)n * 16 + hl];
    float4 a0 = cvt4(us.x, us.y);
    float4 a1 = cvt4(us.z, us.w);
    float4 b0 = make_float4(0.f, 0.f, 0.f, 0.f);
    float4 b1 = make_float4(0.f, 0.f, 0.f, 0.f);

    int j = row_ptr[n], end = row_ptr[n + 1];
    for (; j + 7 < end; j += 8) {
        uint4 u0 = H4[(size_t)srcs[j + 0] * 16 + hl];
        uint4 u1 = H4[(size_t)srcs[j + 1] * 16 + hl];
        uint4 u2 = H4[(size_t)srcs[j + 2] * 16 + hl];
        uint4 u3 = H4[(size_t)srcs[j + 3] * 16 + hl];
        uint4 u4 = H4[(size_t)srcs[j + 4] * 16 + hl];
        uint4 u5 = H4[(size_t)srcs[j + 5] * 16 + hl];
        uint4 u6 = H4[(size_t)srcs[j + 6] * 16 + hl];
        uint4 u7 = H4[(size_t)srcs[j + 7] * 16 + hl];
        float4 t;
        t = cvt4(u0.x, u0.y); a0.x += t.x; a0.y += t.y; a0.z += t.z; a0.w += t.w;
        t = cvt4(u0.z, u0.w); a1.x += t.x; a1.y += t.y; a1.z += t.z; a1.w += t.w;
        t = cvt4(u1.x, u1.y); b0.x += t.x; b0.y += t.y; b0.z += t.z; b0.w += t.w;
        t = cvt4(u1.z, u1.w); b1.x += t.x; b1.y += t.y; b1.z += t.z; b1.w += t.w;
        t = cvt4(u2.x, u2.y); a0.x += t.x; a0.y += t.y; a0.z += t.z; a0.w += t.w;
        t = cvt4(u2.z, u2.w); a1.x += t.x; a1.y += t.y; a1.z += t.z; a1.w += t.w;
        t = cvt4(u3.x, u3.y); b0.x += t.x; b0.y += t.y; b0.z += t.z; b0.w += t.w;
        t = cvt4(u3.z, u3.w); b1.x += t.x; b1.y += t.y; b1.z += t.z; b1.w += t.w;
        t = cvt4(u4.x, u4.y); a0.x += t.x; a0.y += t.y; a0.z += t.z; a0.w += t.w;
        t = cvt4(u4.z, u4.w); a1.x += t.x; a1.y += t.y; a1.z += t.z; a1.w += t.w;
        t = cvt4(u5.x, u5.y); b0.x += t.x; b0.y += t.y; b0.z += t.z; b0.w += t.w;
        t = cvt4(u5.z, u5.w); b1.x += t.x; b1.y += t.y; b1.z += t.z; b1.w += t.w;
        t = cvt4(u6.x, u6.y); a0.x += t.x; a0.y += t.y; a0.z += t.z; a0.w += t.w;
        t = cvt4(u6.z, u6.w); a1.x += t.x; a1.y += t.y; a1.z += t.z; a1.w += t.w;
        t = cvt4(u7.x, u7.y); b0.x += t.x; b0.y += t.y; b0.z += t.z; b0.w += t.w;
        t = cvt4(u7.z, u7.w); b1.x += t.x; b1.y += t.y; b1.z += t.z; b1.w += t.w;
    }
    for (; j + 3 < end; j += 4) {
        uint4 u0 = H4[(size_t)srcs[j + 0] * 16 + hl];
        uint4 u1 = H4[(size_t)srcs[j + 1] * 16 + hl];
        uint4 u2 = H4[(size_t)srcs[j + 2] * 16 + hl];
        uint4 u3 = H4[(size_t)srcs[j + 3] * 16 + hl];
        float4 t;
        t = cvt4(u0.x, u0.y); a0.x += t.x; a0.y += t.y; a0.z += t.z; a0.w += t.w;
        t = cvt4(u0.z, u0.w); a1.x += t.x; a1.y += t.y; a1.z += t.z; a1.w += t.w;
        t = cvt4(u1.x, u1.y); b0.x += t.x; b0.y += t.y; b0.z += t.z; b0.w += t.w;
        t = cvt4(u1.z, u1.w); b1.x += t.x; b1.y += t.y; b1.z += t.z; b1.w += t.w;
        t = cvt4(u2.x, u2.y); a0.x += t.x; a0.y += t.y; a0.z += t.z; a0.w += t.w;
        t = cvt4(u2.z, u2.w); a1.x += t.x; a1.y += t.y; a1.z += t.z; a1.w += t.w;
        t = cvt4(u3.x, u3.y); b0.x += t.x; b0.y += t.y; b0.z += t.z; b0.w += t.w;
        t = cvt4(u3.z, u3.w); b1.x += t.x; b1.y += t.y; b1.z += t.z; b1.w += t.w;
    }
    for (; j < end; ++j) {
        uint4 u = H4[(size_t)srcs[j] * 16 + hl];
        float4 t;
        t = cvt4(u.x, u.y); a0.x += t.x; a0.y += t.y; a0.z += t.z; a0.w += t.w;
        t = cvt4(u.z, u.w); a1.x += t.x; a1.y += t.y; a1.z += t.z; a1.w += t.w;
    }
    a0.x += b0.x; a0.y += b0.y; a0.z += b0.z; a0.w += b0.w;
    a1.x += b1.x; a1.y += b1.y; a1.z += b1.z; a1.w += b1.w;

    float di = dinv[n];
    float4 bv0 = ((const float4*)bias)[2 * hl];
    float4 bv1 = ((const float4*)bias)[2 * hl + 1];
    float o0 = di * a0.x + bv0.x, o1 = di * a0.y + bv0.y;
    float o2 = di * a0.z + bv0.z, o3 = di * a0.w + bv0.w;
    float o4 = di * a1.x + bv1.x, o5 = di * a1.y + bv1.y;
    float o6 = di * a1.z + bv1.z, o7 = di * a1.w + bv1.w;
    if (do_relu) {
        o0 = fmaxf(o0, 0.f); o1 = fmaxf(o1, 0.f); o2 = fmaxf(o2, 0.f); o3 = fmaxf(o3, 0.f);
        o4 = fmaxf(o4, 0.f); o5 = fmaxf(o5, 0.f); o6 = fmaxf(o6, 0.f); o7 = fmaxf(o7, 0.f);
    }
    uint4 o;
    o.x = pack2(o0, o1);
    o.y = pack2(o2, o3);
    o.z = pack2(o4, o5);
    o.w = pack2(o6, o7);
    ((uint4*)Z)[(size_t)n * 16 + hl] = o;
}

// Decode: quarter-wave, 2 pairs per quarter -> 8 pairs/wave.
__global__ __launch_bounds__(256) void decode_kernel(const unsigned short* __restrict__ Z,
                                                     const int* __restrict__ pa,
                                                     const int* __restrict__ pb,
                                                     float* __restrict__ out, int P) {
    int wv = (int)((blockIdx.x * blockDim.x + threadIdx.x) >> 6);
    int lane = threadIdx.x & 63;
    int q = lane >> 4;
    int hl = lane & 15;
    int p0 = wv * 8 + q * 2;
    if (p0 >= P) return;
    const uint4* Z4 = (const uint4*)Z;

    bool two = (p0 + 1 < P);
    int A0 = pa[p0], B0 = pb[p0];
    int A1 = two ? pa[p0 + 1] : A0;
    int B1 = two ? pb[p0 + 1] : B0;
    uint4 ua0 = Z4[(size_t)A0 * 16 + hl];
    uint4 ub0 = Z4[(size_t)B0 * 16 + hl];
    uint4 ua1 = Z4[(size_t)A1 * 16 + hl];
    uint4 ub1 = Z4[(size_t)B1 * 16 + hl];

    float4 xa, xb, ya, yb;
    xa = cvt4(ua0.x, ua0.y); xb = cvt4(ub0.x, ub0.y);
    ya = cvt4(ua0.z, ua0.w); yb = cvt4(ub0.z, ub0.w);
    float v0 = xa.x * xb.x + xa.y * xb.y + xa.z * xb.z + xa.w * xb.w
             + ya.x * yb.x + ya.y * yb.y + ya.z * yb.z + ya.w * yb.w;
    xa = cvt4(ua1.x, ua1.y); xb = cvt4(ub1.x, ub1.y);
    ya = cvt4(ua1.z, ua1.w); yb = cvt4(ub1.z, ub1.w);
    float v1 = xa.x * xb.x + xa.y * xb.y + xa.z * xb.z + xa.w * xb.w
             + ya.x * yb.x + ya.y * yb.y + ya.z * yb.z + ya.w * yb.w;
#pragma unroll
    for (int off = 8; off > 0; off >>= 1) {
        v0 += __shfl_down(v0, off, 16);
        v1 += __shfl_down(v1, off, 16);
    }
    if (hl == 0) {
        out[p0] = v0;
        if (two) out[p0 + 1] = v1;
    }
}

extern "C" void kernel_launch(void* const* d_in, const int* in_sizes, int n_in,
                              void* d_out, int out_size, void* d_ws, size_t ws_size,
                              hipStream_t stream) {
    const int*   edge_index = (const int*)d_in[0];
    const int*   edge_pairs = (const int*)d_in[1];
    const float* emb        = (const float*)d_in[2];
    const float* W1         = (const float*)d_in[3];
    const float* b1         = (const float*)d_in[4];
    const float* W2         = (const float*)d_in[5];
    const float* b2         = (const float*)d_in[6];
    float* out = (float*)d_out;

    int E = in_sizes[0] / 2;
    int P = in_sizes[1] / 2;
    int N = in_sizes[2] / 128;
    int NB = (N + 63) / 64;    // buckets == gemm tiles (782 for N=50000; must be <= 1024)

    const int* src = edge_index;
    const int* dst = edge_index + E;
    const int* pa  = edge_pairs;
    const int* pb  = edge_pairs + P;

    char* ws = (char*)d_ws;
    size_t off = 0;
    auto alloc = [&](size_t bytes) -> void* {
        void* p = ws + off;
        off = (off + bytes + 255) & ~(size_t)255;
        return p;
    };
    unsigned short* bufA = (unsigned short*)alloc((size_t)N * 128 * 2); // h1' then h2'
    unsigned short* bufB = (unsigned short*)alloc((size_t)N * 128 * 2); // z1 then z2
    int*   srcs_sorted  = (int*)alloc((size_t)E * sizeof(int));
    unsigned int* stage = (unsigned int*)alloc((size_t)E * sizeof(unsigned int));
    int*   row_ptr      = (int*)alloc((size_t)(N + 1) * sizeof(int));
    float* dinv         = (float*)alloc((size_t)N * sizeof(float));
    int*   bhist        = (int*)alloc((size_t)STAGE_G * NB * sizeof(int));
    int*   T            = (int*)alloc((size_t)NB * sizeof(int));
    int*   bucket_base  = (int*)alloc((size_t)(NB + 1) * sizeof(int));

    // CSR build front half (3 dispatches)
    block_hist_kernel<<<STAGE_G, 256, 0, stream>>>(dst, bhist, E, NB);
    s1_scan_blocks<<<NB, 128, 0, stream>>>(bhist, T, NB);
    stage_kernel<<<STAGE_G, 256, 0, stream>>>(src, dst, bhist, T, bucket_base, stage, E, NB);

    // FUSED scatter + gemm1: CSR finalize + h1' = dinv*(emb@W1) -> bufA
    scatter_gemm_kernel<<<NB, 256, 0, stream>>>(stage, bucket_base, row_ptr, dinv,
                                                srcs_sorted, emb, W1, (uint2*)bufA, N);

    // agg1: z1 = relu(dinv*(h1'+sum)+b1) -> bufB
    agg_kernel<<<(N + 15) / 16, 256, 0, stream>>>(bufA, row_ptr, srcs_sorted, dinv, b1,
                                                  bufB, N, 1);

    // gemm2: h2' = dinv*(z1@W2) -> bufA
    gemm_mfma_kernel<<<NB, 256, 0, stream>>>(bufB, W2, dinv, (uint2*)bufA, N);

    // agg2: z2 = dinv*(h2'+sum)+b2 -> bufB
    agg_kernel<<<(N + 15) / 16, 256, 0, stream>>>(bufA, row_ptr, srcs_sorted, dinv, b2,
                                                  bufB, N, 0);

    // Decode: 8 pairs/wave
    decode_kernel<<<(P + 31) / 32, 256, 0, stream>>>(bufB, pa, pb, out, P);
}